// Round 12
// baseline (1632.530 us; speedup 1.0000x reference)
//
#include <hip/hip_runtime.h>
#include <math.h>

typedef unsigned long long u64;
typedef unsigned int u32;

#define HH 160
#define WW 160
#define CC 256
#define NPX 25600
#define NA 9
#define NSC 230400
#define K_SEL 6000
#define SEL_PAD 6016
#define IMS 2560.0f
#define DWH 4.135166556742356f

struct SelState { u64 prefix; u32 r; u32 cnt; };

// ---- ws layout (bytes) ----
#define OFF_BOXES   0u               // float4[230400] -> 3,686,400
#define OFF_SCORES  3686400u         // float [230400]
#define OFF_KEYS    4608000u         // u64   [230400]
#define OFF_STATE   7499776u
#define OFF_SELK    7500032u         // u64[6016]
#define OFF_SX1     7548160u
#define OFF_SY1     7572224u
#define OFF_SX2     7596288u
#define OFF_SY2     7620352u
#define OFF_SSC     7644416u
#define OFF_MASKR   11503104u        // u64[6016*94] row-major -> 4,524,032 (fits old maskT slot)
#define OFF_WT      16028160u        // float[2304*256] -> ends 18,387,456
#define OFF_HIST    18387456u        // u32[5*8192] -> ends 18,551,296
#define OFF_RPN     27869184u        // float[256*160*160] -> ends 54,083,584

__constant__ float c_bx1[9] = {-91.f,-181.f,-362.f,-64.f,-128.f,-256.f,-45.f,-91.f,-181.f};
__constant__ float c_by1[9] = {-45.f,-91.f,-181.f,-64.f,-128.f,-256.f,-91.f,-181.f,-362.f};
__constant__ float c_bx2[9] = { 91.f, 181.f, 362.f, 64.f, 128.f, 256.f, 45.f, 91.f, 181.f};
__constant__ float c_by2[9] = { 45.f,  91.f, 181.f, 64.f, 128.f, 256.f, 91.f, 181.f, 362.f};

__device__ inline u64 shfl64(u64 v, int src) {
  int lo = (int)(v & 0xFFFFFFFFull), hi = (int)(v >> 32);
  lo = __shfl(lo, src, 64); hi = __shfl(hi, src, 64);
  return ((u64)(u32)hi << 32) | (u32)lo;
}

// ---------------- 0. weight transpose FUSED with hist/state zeroing ----------------
__global__ __launch_bounds__(256) void wtrz_k(const float* __restrict__ w, float* __restrict__ wT,
                                              u32* __restrict__ hist, SelState* st) {
  int b = blockIdx.x;
  int tid = threadIdx.x;
  if (b < 144) {
    __shared__ float t[64][65];
    int kb = b % 36;
    int ob = b / 36;
    for (int it = 0; it < 16; it++) {
      int idx = it * 256 + tid;
      int row = idx >> 6, colk = idx & 63;
      t[row][colk] = w[(size_t)(ob * 64 + row) * 2304 + kb * 64 + colk];
    }
    __syncthreads();
    for (int it = 0; it < 16; it++) {
      int idx = it * 256 + tid;
      int krow = idx >> 6, occ = idx & 63;
      wT[(size_t)(kb * 64 + krow) * 256 + ob * 64 + occ] = t[occ][krow];
    }
  } else {
    int zb = (b - 144) * 1024 + tid * 4;      // 40 blocks x 1024 = 40960 = 5*8192
    *(uint4*)&hist[zb] = make_uint4(0, 0, 0, 0);
    if (b == 144 && tid == 0) { st->prefix = 0; st->r = K_SEL; st->cnt = 0; }
  }
}

// ---------------- 1. conv3x3 + bias + relu (R1 scalar-weight, frozen at ~504us) ----------------
__global__ __launch_bounds__(256) void conv_k(const float* __restrict__ feat,
                                              const float* __restrict__ wT,
                                              const float* __restrict__ bias,
                                              float* __restrict__ outp) {
  int bx = blockIdx.x;              // 800 = 5 * 40 * 4
  int ct = bx % 5;
  int rt = (bx / 5) % 40;
  int ot = bx / 200;
  int x0 = ct * 32, y0 = rt * 4, oc0 = ot * 64;

  __shared__ float ps[2][8][6][36];

  int tid = threadIdx.x;
  int lane = tid & 63;
  int wvu = __builtin_amdgcn_readfirstlane(tid >> 6);   // wave id, SGPR-uniform
  int col = lane & 31;
  int s = lane >> 5;
  int ocw = oc0 + wvu * 16;

  int s_off[7]; int s_lof[7]; bool s_val[7];
#pragma unroll
  for (int it = 0; it < 7; it++) {
    int idx = tid + it * 256;
    bool ex = (idx < 1632);
    int icl = idx / 204, rem = idx % 204;
    int r = rem / 34, c = rem % 34;
    int gy = y0 + r - 1, gx = x0 + c - 1;
    s_val[it] = ex && ((unsigned)gy < 160u) && ((unsigned)gx < 160u);
    s_off[it] = icl * NPX + gy * WW + gx;
    s_lof[it] = ex ? ((icl * 6 + r) * 36 + c) : 0;
    if (!ex) s_lof[it] = -1;
  }

  float acc0[16], acc1[16];
#pragma unroll
  for (int i = 0; i < 16; i++) { acc0[i] = 0.f; acc1[i] = 0.f; }

  float st[7];
#pragma unroll
  for (int it = 0; it < 7; it++) {
    float v = 0.f;
    if (s_val[it]) v = feat[s_off[it]];
    if (s_lof[it] >= 0) (&ps[0][0][0][0])[s_lof[it]] = v;
  }
  __syncthreads();

  for (int c8 = 0; c8 < 32; c8++) {
    if (c8 < 31) {
      int icn = (c8 + 1) * 8;
#pragma unroll
      for (int it = 0; it < 7; it++) {
        st[it] = 0.f;
        if (s_val[it]) st[it] = feat[icn * NPX + s_off[it]];
      }
    }
    int buf = c8 & 1;
    int ic0 = c8 * 8;
    for (int icl = 0; icl < 8; icl++) {       // not unrolled: I-cache
      float p[4][3];
#pragma unroll
      for (int rr = 0; rr < 4; rr++)
#pragma unroll
        for (int cc = 0; cc < 3; cc++)
          p[rr][cc] = ps[buf][icl][2 * s + rr][col + cc];
      const float* wb = wT + (size_t)(ic0 + icl) * 9 * 256 + ocw;   // uniform addr
#pragma unroll
      for (int dy = 0; dy < 3; dy++) {
#pragma unroll
        for (int dx = 0; dx < 3; dx++) {
          const float* wr = wb + (dy * 3 + dx) * 256;
#pragma unroll
          for (int i = 0; i < 16; i++) {
            float wv_ = wr[i];                // s_load -> SGPR operand
            acc0[i] += wv_ * p[dy][dx];
            acc1[i] += wv_ * p[dy + 1][dx];
          }
        }
      }
    }
    if (c8 < 31) {
      __syncthreads();
      float* dst = &ps[buf ^ 1][0][0][0];
#pragma unroll
      for (int it = 0; it < 7; it++)
        if (s_lof[it] >= 0) dst[s_lof[it]] = st[it];
      __syncthreads();
    }
  }
#pragma unroll
  for (int i = 0; i < 16; i++) {
    int oc = ocw + i;
    float bv = bias[oc];
    size_t base = (size_t)oc * NPX + (y0 + 2 * s) * WW + x0 + col;
    outp[base] = fmaxf(acc0[i] + bv, 0.f);
    outp[base + WW] = fmaxf(acc1[i] + bv, 0.f);
  }
}

// ---------------- 2. heads + sigmoid + decode + clip + key ----------------
__global__ __launch_bounds__(256) void heads_k(const float* __restrict__ rpn,
                                               const float* __restrict__ cls_w,
                                               const float* __restrict__ cls_b,
                                               const float* __restrict__ bbox_w,
                                               const float* __restrict__ bbox_b,
                                               float4* __restrict__ boxes,
                                               float* __restrict__ scores,
                                               u64* __restrict__ keys) {
  __shared__ float sf[32][260];
  __shared__ float so[45][33];
  int tid = threadIdx.x;
  int px0 = blockIdx.x * 32;
  for (int idx = tid; idx < 8192; idx += 256) {
    int c = idx >> 5, p = idx & 31;
    sf[p][c] = rpn[(size_t)c * NPX + px0 + p];
  }
  __syncthreads();
  int p = tid & 31, g = tid >> 5;
  for (int oi = 0; oi < 6; oi++) {
    int o = g + oi * 8;
    if (o >= 45) break;
    const float* wr = (o < 9) ? (cls_w + o * CC) : (bbox_w + (o - 9) * CC);
    float bsum = (o < 9) ? cls_b[o] : bbox_b[o - 9];
    float s = 0.f;
    for (int c = 0; c < CC; c += 4) {
      float4 f = *(const float4*)&sf[p][c];
      float4 wv = *(const float4*)&wr[c];
      s += f.x * wv.x; s += f.y * wv.y; s += f.z * wv.z; s += f.w * wv.w;
    }
    so[o][p] = s + bsum;
  }
  __syncthreads();
  for (int t = tid; t < 288; t += 256) {
    int a = t >> 5, pp = t & 31;
    int px = px0 + pp;
    int y = px / 160, x = px - y * 160;
    float logit = so[a][pp];
    float sc = 1.f / (1.f + expf(-logit));
    float ddx = so[9 + 4 * a][pp], ddy = so[10 + 4 * a][pp];
    float ddw = fminf(so[11 + 4 * a][pp], DWH);
    float ddh = fminf(so[12 + 4 * a][pp], DWH);
    float ax1 = x * 16.f + c_bx1[a];
    float ay1 = y * 16.f + c_by1[a];
    float ax2 = x * 16.f + c_bx2[a];
    float ay2 = y * 16.f + c_by2[a];
    float aw = ax2 - ax1, ah = ay2 - ay1;
    float cx = ax1 + 0.5f * aw, cy = ay1 + 0.5f * ah;
    float pcx = ddx * aw + cx, pcy = ddy * ah + cy;
    float pw = expf(ddw) * aw, phh = expf(ddh) * ah;
    float x1 = pcx - 0.5f * pw, y1 = pcy - 0.5f * phh;
    float x2 = pcx + 0.5f * pw, y2 = pcy + 0.5f * phh;
    x1 = fminf(fmaxf(x1, 0.f), IMS); x2 = fminf(fmaxf(x2, 0.f), IMS);
    y1 = fminf(fmaxf(y1, 0.f), IMS); y2 = fminf(fmaxf(y2, 0.f), IMS);
    int gidx = px * 9 + a;
    boxes[gidx] = make_float4(x1, y1, x2, y2);
    scores[gidx] = sc;
    u32 sb = __float_as_uint(sc);
    u32 mono = (sb & 0x80000000u) ? ~sb : (sb | 0x80000000u);
    keys[gidx] = ((u64)mono << 32) | (u64)(0xFFFFFFFFu - (u32)gidx);
  }
}

// ---------------- 3. grid-wide radix select (R8 split hist/scan) ----------------
__global__ __launch_bounds__(256) void hist_k(const u64* __restrict__ keys,
                                              const SelState* __restrict__ st,
                                              u32* __restrict__ hist,
                                              int wbits, int bitsdone) {
  int idx = blockIdx.x * 256 + threadIdx.x;  // grid 900 -> exactly 230400
  int lane = threadIdx.x & 63;
  u64 k = keys[idx];
  int shift = 64 - bitsdone - wbits;
  bool active = true;
  if (bitsdone > 0) active = ((k >> (64 - bitsdone)) == st->prefix);
  u32 digit = (u32)((k >> shift) & (u64)((1 << wbits) - 1));
  u64 act = __ballot(active);
  u64 todo = act;
  while (todo) {
    int src = __builtin_ctzll(todo);
    u32 d0 = (u32)__shfl((int)digit, src, 64);
    u64 m = __ballot(digit == d0) & act;
    if (lane == src) atomicAdd(&hist[d0], (u32)__popcll(m & todo));
    todo &= ~m;
  }
}

__global__ __launch_bounds__(1024) void scan_k(const u32* __restrict__ hist,
                                               SelState* st, int wbits) {
  __shared__ u32 tsum[1024];
  __shared__ u32 wsum[16];
  int tid = threadIdx.x;
  int lane = tid & 63, wv = tid >> 6;
  int nbins = 1 << wbits;
  int bpt = nbins >> 10;
  u32 r = st->r;
  u32 s = 0;
  for (int b = 0; b < bpt; b++) s += hist[tid * bpt + b];
  tsum[tid] = s;
  u32 v = s;
#pragma unroll
  for (int off = 1; off < 64; off <<= 1) v += (u32)__shfl_xor((int)v, off, 64);
  if (lane == 0) wsum[wv] = v;
  __syncthreads();
  if (tid == 0) {
    u32 cum = 0;
    int ws = 15;
    while (ws > 0 && cum + wsum[ws] < r) { cum += wsum[ws]; ws--; }
    int t = ws * 64 + 63, tend = ws * 64;
    while (t > tend && cum + tsum[t] < r) { cum += tsum[t]; t--; }
    int b = t * bpt + bpt - 1, bend = t * bpt;
    while (b > bend && cum + hist[b] < r) { cum += hist[b]; b--; }
    st->prefix = (st->prefix << wbits) | (u64)(u32)b;
    st->r = r - cum;
  }
}

// ---------------- 3b. compact: block-aggregated atomic ----------------
__global__ __launch_bounds__(256) void compact_k(const u64* __restrict__ keys,
                                                 SelState* st, u64* __restrict__ selk) {
  __shared__ u32 wbase[4];
  __shared__ u32 blkbase;
  int tid = threadIdx.x;
  int lane = tid & 63, wv = tid >> 6;
  int idx = blockIdx.x * 256 + tid;
  u64 k = keys[idx];
  bool sel = (k >= st->prefix);
  u64 m = __ballot(sel);
  u32 wcnt = (u32)__popcll(m);
  u32 before = (u32)__popcll(m & ((1ull << lane) - 1ull));
  if (lane == 0) wbase[wv] = wcnt;
  __syncthreads();
  if (tid == 0) {
    u32 b0 = wbase[0], b1 = wbase[1], b2 = wbase[2], b3 = wbase[3];
    u32 tot = b0 + b1 + b2 + b3;
    blkbase = tot ? atomicAdd(&st->cnt, tot) : 0u;
    wbase[0] = 0; wbase[1] = b0; wbase[2] = b0 + b1; wbase[3] = b0 + b1 + b2;
  }
  __syncthreads();
  if (sel) selk[blkbase + wbase[wv] + before] = k;
}

// ---------------- 4. exact rank -> sorted SoA ----------------
__global__ __launch_bounds__(64) void rank_k(const u64* __restrict__ selk,
                                             const float4* __restrict__ boxes,
                                             const float* __restrict__ scores,
                                             float* sx1, float* sy1, float* sx2, float* sy2, float* ssc) {
  __shared__ __align__(16) u64 sk[SEL_PAD];
  int lane = threadIdx.x;
  for (int i = lane; i < SEL_PAD; i += 64) sk[i] = (i < K_SEL) ? selk[i] : 0ull;
  __syncthreads();
  int n = blockIdx.x * 64 + lane;
  u64 myk = (n < K_SEL) ? selk[n] : ~0ull;
  int cnt = 0;
  const ulonglong2* sk2 = (const ulonglong2*)sk;
#pragma unroll 8
  for (int j = 0; j < SEL_PAD / 2; j++) {
    ulonglong2 kk = sk2[j];
    cnt += (kk.x > myk) ? 1 : 0;
    cnt += (kk.y > myk) ? 1 : 0;
  }
  if (n < K_SEL) {
    u32 oidx = 0xFFFFFFFFu - (u32)(myk & 0xFFFFFFFFull);
    float4 b = boxes[oidx];
    sx1[cnt] = b.x; sy1[cnt] = b.y; sx2[cnt] = b.z; sy2[cnt] = b.w;
    ssc[cnt] = scores[oidx];
  }
}

// ---------------- 5. pairwise suppression mask (ROW-major: maskR[i][w]) ----------------
// Same ballot bits as before; stored row-major so nms can fetch a kept
// proposal's whole suppression row as 94 contiguous u64 (752B, coalesced).
__global__ __launch_bounds__(256) void mask_k(const float* __restrict__ sx1, const float* __restrict__ sy1,
                                              const float* __restrict__ sx2, const float* __restrict__ sy2,
                                              u64* __restrict__ maskR) {
  __shared__ float jb[5][3008];
  int tid = threadIdx.x;
  int wv = tid >> 6, lane = tid & 63;
  int ibase = blockIdx.x * 32 + wv * 8;
  float ix1[8], iy1[8], ix2[8], iy2[8], ia[8];
#pragma unroll
  for (int r = 0; r < 8; r++) {
    int i = ibase + r;
    ix1[r] = sx1[i]; iy1[r] = sy1[i]; ix2[r] = sx2[i]; iy2[r] = sy2[i];
    ia[r] = (ix2[r] - ix1[r]) * (iy2[r] - iy1[r]);
  }
  for (int half = 0; half < 2; half++) {
    int j0 = half * 3008;
    __syncthreads();
    for (int idx = tid; idx < 3008; idx += 256) {
      int j = j0 + idx;
      bool v = j < K_SEL;
      float a = v ? sx1[j] : 0.f;
      float b = v ? sy1[j] : 0.f;
      float c = v ? sx2[j] : 0.f;
      float d = v ? sy2[j] : 0.f;
      jb[0][idx] = a; jb[1][idx] = b; jb[2][idx] = c; jb[3][idx] = d;
      jb[4][idx] = (c - a) * (d - b);
    }
    __syncthreads();
    for (int wi = 0; wi < 47; wi++) {
      int w = half * 47 + wi;
      int jl = wi * 64 + lane;
      int j = j0 + jl;
      float jx1 = jb[0][jl], jy1 = jb[1][jl], jx2 = jb[2][jl], jy2 = jb[3][jl], ja = jb[4][jl];
      bool jv = j < K_SEL;
#pragma unroll
      for (int r = 0; r < 8; r++) {
        int i = ibase + r;
        float xl = fmaxf(ix1[r], jx1), yt = fmaxf(iy1[r], jy1);
        float xr = fminf(ix2[r], jx2), yb = fminf(iy2[r], jy2);
        float iw = fmaxf(xr - xl, 0.f), ihh = fmaxf(yb - yt, 0.f);
        float inter = iw * ihh;
        bool sup = jv && (j > i) && (inter > 0.7f * (ia[r] + ja - inter));
        u64 bits = __ballot(sup);
        if (lane == 0 && i < K_SEL) maskR[(size_t)i * 94 + w] = bits;
      }
    }
  }
}

// ---------------- 6. greedy NMS (incremental dead-bitmap) + finalize ----------------
// Old nms re-scanned the full 94x6016 mask per column (4.5MB single-block
// traffic + 1024-thread reduce + 3 barriers x 94). New: dead[94] bitmap in
// LDS; per column read dead[c] (replaces the scan), same greedy walk, then
// OR only the KEPT rows (94 contiguous u64 each, parallel across 16 waves,
// LDS atomicOr). dead == OR of previously-kept suppression rows == old supp
// -> identical kept set -> absmax 0.0. Rows >= K_SEL are never read (svalid
// masks them; shfl only selects valid bits).
__global__ __launch_bounds__(1024) void nmsf_k(const u64* __restrict__ maskR,
                                               const float* __restrict__ sx1, const float* __restrict__ sy1,
                                               const float* __restrict__ sx2, const float* __restrict__ sy2,
                                               const float* __restrict__ ssc, float* __restrict__ out) {
  __shared__ u64 sdiag[94 * 64];
  __shared__ u64 skept[96];
  __shared__ u64 svalid[94];
  __shared__ u32 dead32[188];
  __shared__ int klist[64];
  __shared__ int kcnt;
  __shared__ u32 pre[95];
  int tid = threadIdx.x;
  int wv = tid >> 6, lane = tid & 63;

  if (tid < 96) skept[tid] = 0ull;
  if (tid < 188) dead32[tid] = 0u;
  for (int w = wv; w < 94; w += 16) {
    int p = w * 64 + lane;
    float bw = sx2[p] - sx1[p], bh = sy2[p] - sy1[p];
    bool ok = (p < K_SEL) && (bw >= 16.f) && (bh >= 16.f);
    u64 bits = __ballot(ok);
    if (lane == 0) svalid[w] = bits;
  }
  for (int idx = tid; idx < 94 * 64; idx += 1024) {
    int cc = idx >> 6, l = idx & 63;
    sdiag[idx] = maskR[(size_t)(cc * 64 + l) * 94 + cc];
  }
  __syncthreads();

  for (int c = 0; c < 94; c++) {
    if (wv == 0) {
      u64 deadc = ((u64)dead32[2 * c + 1] << 32) | (u64)dead32[2 * c];
      u64 cur = svalid[c] & ~deadc;
      u64 d = sdiag[c * 64 + lane];
      u64 rem = cur, kept = 0;
      int n = 0;
      while (rem) {
        int b = __builtin_ctzll(rem);
        kept |= (1ull << b);
        if (lane == 0) klist[n] = b;
        n++;
        u64 dd = shfl64(d, b);
        rem &= ~dd;
        rem &= ~(1ull << b);
      }
      if (lane == 0) { skept[c] = kept; kcnt = n; }
    }
    __syncthreads();
    int n = kcnt;
    for (int ki = wv; ki < n; ki += 16) {
      const u64* row = maskR + (size_t)(c * 64 + klist[ki]) * 94;
      u64 r0 = row[lane];
      atomicOr(&dead32[2 * lane], (u32)r0);
      atomicOr(&dead32[2 * lane + 1], (u32)(r0 >> 32));
      if (lane < 30) {
        u64 r1 = row[64 + lane];
        atomicOr(&dead32[2 * (64 + lane)], (u32)r1);
        atomicOr(&dead32[2 * (64 + lane) + 1], (u32)(r1 >> 32));
      }
    }
    __syncthreads();
  }

  // ---- finalize (identical outputs to split final_k) ----
  if (tid == 0) {
    u32 s = 0;
    for (int w = 0; w < 94; w++) { pre[w] = s; s += (u32)__popcll(skept[w]); }
    pre[94] = s;
  }
  __syncthreads();
  u32 total = pre[94];
  for (int p = tid; p < K_SEL; p += 1024) {
    int w = p >> 6, b = p & 63;
    u64 word = skept[w];
    u32 kb = pre[w] + (u32)__popcll(word & ((1ull << b) - 1ull));
    bool kept = (word >> b) & 1ull;
    int slot = -1; float sc = -1.f;
    if (kept) {
      if (kb < 300) { slot = (int)kb; sc = ssc[p]; }
    } else {
      u32 s2 = total + (u32)p - kb;
      if (s2 < 300) slot = (int)s2;
    }
    if (slot >= 0) {
      out[slot * 5 + 0] = sx1[p];
      out[slot * 5 + 1] = sy1[p];
      out[slot * 5 + 2] = sx2[p];
      out[slot * 5 + 3] = sy2[p];
      out[slot * 5 + 4] = sc;
    }
  }
}

extern "C" void kernel_launch(void* const* d_in, const int* in_sizes, int n_in,
                              void* d_out, int out_size, void* d_ws, size_t ws_size,
                              hipStream_t stream) {
  const float* feat   = (const float*)d_in[0];
  const float* conv_w = (const float*)d_in[2];
  const float* conv_b = (const float*)d_in[3];
  const float* cls_w  = (const float*)d_in[4];
  const float* cls_b  = (const float*)d_in[5];
  const float* bbox_w = (const float*)d_in[6];
  const float* bbox_b = (const float*)d_in[7];
  float* out = (float*)d_out;
  char* ws = (char*)d_ws;

  float*  rpn    = (float*)(ws + OFF_RPN);
  float4* boxes  = (float4*)(ws + OFF_BOXES);
  float*  scores = (float*)(ws + OFF_SCORES);
  u64*    keys   = (u64*)(ws + OFF_KEYS);
  SelState* st   = (SelState*)(ws + OFF_STATE);
  u64*    selk   = (u64*)(ws + OFF_SELK);
  float*  sx1    = (float*)(ws + OFF_SX1);
  float*  sy1    = (float*)(ws + OFF_SY1);
  float*  sx2    = (float*)(ws + OFF_SX2);
  float*  sy2    = (float*)(ws + OFF_SY2);
  float*  ssc    = (float*)(ws + OFF_SSC);
  u64*    maskR  = (u64*)(ws + OFF_MASKR);
  float*  wT     = (float*)(ws + OFF_WT);
  u32*    hist   = (u32*)(ws + OFF_HIST);

  wtrz_k<<<184, 256, 0, stream>>>(conv_w, wT, hist, st);
  conv_k<<<800, 256, 0, stream>>>(feat, wT, conv_b, rpn);
  heads_k<<<800, 256, 0, stream>>>(rpn, cls_w, cls_b, bbox_w, bbox_b, boxes, scores, keys);

  hist_k<<<900, 256, 0, stream>>>(keys, st, hist,         13,  0);
  scan_k<<<1, 1024, 0, stream>>>(hist,         st, 13);
  hist_k<<<900, 256, 0, stream>>>(keys, st, hist +  8192, 13, 13);
  scan_k<<<1, 1024, 0, stream>>>(hist +  8192, st, 13);
  hist_k<<<900, 256, 0, stream>>>(keys, st, hist + 16384, 13, 26);
  scan_k<<<1, 1024, 0, stream>>>(hist + 16384, st, 13);
  hist_k<<<900, 256, 0, stream>>>(keys, st, hist + 24576, 13, 39);
  scan_k<<<1, 1024, 0, stream>>>(hist + 24576, st, 13);
  hist_k<<<900, 256, 0, stream>>>(keys, st, hist + 32768, 12, 52);
  scan_k<<<1, 1024, 0, stream>>>(hist + 32768, st, 12);

  compact_k<<<900, 256, 0, stream>>>(keys, st, selk);
  rank_k<<<94, 64, 0, stream>>>(selk, boxes, scores, sx1, sy1, sx2, sy2, ssc);
  mask_k<<<188, 256, 0, stream>>>(sx1, sy1, sx2, sy2, maskR);
  nmsf_k<<<1, 1024, 0, stream>>>(maskR, sx1, sy1, sx2, sy2, ssc, out);
}

// Round 13
// 1398.249 us; speedup vs baseline: 1.1676x; 1.1676x over previous
//
#include <hip/hip_runtime.h>
#include <math.h>

typedef unsigned long long u64;
typedef unsigned int u32;

#define HH 160
#define WW 160
#define CC 256
#define NPX 25600
#define NA 9
#define NSC 230400
#define K_SEL 6000
#define SEL_PAD 6016
#define IMS 2560.0f
#define DWH 4.135166556742356f

struct SelState { u64 prefix; u32 r; u32 cnt; };

// ---- ws layout (bytes) ----
#define OFF_BOXES   0u               // float4[230400] -> 3,686,400
#define OFF_SCORES  3686400u         // float [230400]
#define OFF_KEYS    4608000u         // u64   [230400]
#define OFF_STATE   7499776u
#define OFF_SELK    7500032u         // u64[6016]
#define OFF_SX1     7548160u
#define OFF_SY1     7572224u
#define OFF_SX2     7596288u
#define OFF_SY2     7620352u
#define OFF_SSC     7644416u
#define OFF_MASKR   11503104u        // u64[6016*94] row-major -> 4,524,032
#define OFF_WT      16028160u        // float[2304*256] -> ends 18,387,456
#define OFF_HIST    18387456u        // u32[5*8192] -> ends 18,551,296
#define OFF_RPN     27869184u        // float[256*160*160] -> ends 54,083,584

__constant__ float c_bx1[9] = {-91.f,-181.f,-362.f,-64.f,-128.f,-256.f,-45.f,-91.f,-181.f};
__constant__ float c_by1[9] = {-45.f,-91.f,-181.f,-64.f,-128.f,-256.f,-91.f,-181.f,-362.f};
__constant__ float c_bx2[9] = { 91.f, 181.f, 362.f, 64.f, 128.f, 256.f, 45.f, 91.f, 181.f};
__constant__ float c_by2[9] = { 45.f,  91.f, 181.f, 64.f, 128.f, 256.f, 91.f, 181.f, 362.f};

__device__ inline u64 shfl64(u64 v, int src) {
  int lo = (int)(v & 0xFFFFFFFFull), hi = (int)(v >> 32);
  lo = __shfl(lo, src, 64); hi = __shfl(hi, src, 64);
  return ((u64)(u32)hi << 32) | (u32)lo;
}

// ---------------- 0. weight transpose FUSED with hist/state zeroing ----------------
__global__ __launch_bounds__(256) void wtrz_k(const float* __restrict__ w, float* __restrict__ wT,
                                              u32* __restrict__ hist, SelState* st) {
  int b = blockIdx.x;
  int tid = threadIdx.x;
  if (b < 144) {
    __shared__ float t[64][65];
    int kb = b % 36;
    int ob = b / 36;
    for (int it = 0; it < 16; it++) {
      int idx = it * 256 + tid;
      int row = idx >> 6, colk = idx & 63;
      t[row][colk] = w[(size_t)(ob * 64 + row) * 2304 + kb * 64 + colk];
    }
    __syncthreads();
    for (int it = 0; it < 16; it++) {
      int idx = it * 256 + tid;
      int krow = idx >> 6, occ = idx & 63;
      wT[(size_t)(kb * 64 + krow) * 256 + ob * 64 + occ] = t[occ][krow];
    }
  } else {
    int zb = (b - 144) * 1024 + tid * 4;      // 40 blocks x 1024 = 40960 = 5*8192
    *(uint4*)&hist[zb] = make_uint4(0, 0, 0, 0);
    if (b == 144 && tid == 0) { st->prefix = 0; st->r = K_SEL; st->cnt = 0; }
  }
}

// ---------------- 1. conv3x3 + bias + relu (R1 scalar-weight, frozen at ~504us) ----------------
__global__ __launch_bounds__(256) void conv_k(const float* __restrict__ feat,
                                              const float* __restrict__ wT,
                                              const float* __restrict__ bias,
                                              float* __restrict__ outp) {
  int bx = blockIdx.x;              // 800 = 5 * 40 * 4
  int ct = bx % 5;
  int rt = (bx / 5) % 40;
  int ot = bx / 200;
  int x0 = ct * 32, y0 = rt * 4, oc0 = ot * 64;

  __shared__ float ps[2][8][6][36];

  int tid = threadIdx.x;
  int lane = tid & 63;
  int wvu = __builtin_amdgcn_readfirstlane(tid >> 6);   // wave id, SGPR-uniform
  int col = lane & 31;
  int s = lane >> 5;
  int ocw = oc0 + wvu * 16;

  int s_off[7]; int s_lof[7]; bool s_val[7];
#pragma unroll
  for (int it = 0; it < 7; it++) {
    int idx = tid + it * 256;
    bool ex = (idx < 1632);
    int icl = idx / 204, rem = idx % 204;
    int r = rem / 34, c = rem % 34;
    int gy = y0 + r - 1, gx = x0 + c - 1;
    s_val[it] = ex && ((unsigned)gy < 160u) && ((unsigned)gx < 160u);
    s_off[it] = icl * NPX + gy * WW + gx;
    s_lof[it] = ex ? ((icl * 6 + r) * 36 + c) : 0;
    if (!ex) s_lof[it] = -1;
  }

  float acc0[16], acc1[16];
#pragma unroll
  for (int i = 0; i < 16; i++) { acc0[i] = 0.f; acc1[i] = 0.f; }

  float st[7];
#pragma unroll
  for (int it = 0; it < 7; it++) {
    float v = 0.f;
    if (s_val[it]) v = feat[s_off[it]];
    if (s_lof[it] >= 0) (&ps[0][0][0][0])[s_lof[it]] = v;
  }
  __syncthreads();

  for (int c8 = 0; c8 < 32; c8++) {
    if (c8 < 31) {
      int icn = (c8 + 1) * 8;
#pragma unroll
      for (int it = 0; it < 7; it++) {
        st[it] = 0.f;
        if (s_val[it]) st[it] = feat[icn * NPX + s_off[it]];
      }
    }
    int buf = c8 & 1;
    int ic0 = c8 * 8;
    for (int icl = 0; icl < 8; icl++) {       // not unrolled: I-cache
      float p[4][3];
#pragma unroll
      for (int rr = 0; rr < 4; rr++)
#pragma unroll
        for (int cc = 0; cc < 3; cc++)
          p[rr][cc] = ps[buf][icl][2 * s + rr][col + cc];
      const float* wb = wT + (size_t)(ic0 + icl) * 9 * 256 + ocw;   // uniform addr
#pragma unroll
      for (int dy = 0; dy < 3; dy++) {
#pragma unroll
        for (int dx = 0; dx < 3; dx++) {
          const float* wr = wb + (dy * 3 + dx) * 256;
#pragma unroll
          for (int i = 0; i < 16; i++) {
            float wv_ = wr[i];                // s_load -> SGPR operand
            acc0[i] += wv_ * p[dy][dx];
            acc1[i] += wv_ * p[dy + 1][dx];
          }
        }
      }
    }
    if (c8 < 31) {
      __syncthreads();
      float* dst = &ps[buf ^ 1][0][0][0];
#pragma unroll
      for (int it = 0; it < 7; it++)
        if (s_lof[it] >= 0) dst[s_lof[it]] = st[it];
      __syncthreads();
    }
  }
#pragma unroll
  for (int i = 0; i < 16; i++) {
    int oc = ocw + i;
    float bv = bias[oc];
    size_t base = (size_t)oc * NPX + (y0 + 2 * s) * WW + x0 + col;
    outp[base] = fmaxf(acc0[i] + bv, 0.f);
    outp[base + WW] = fmaxf(acc1[i] + bv, 0.f);
  }
}

// ---------------- 2. heads + sigmoid + decode + clip + key ----------------
__global__ __launch_bounds__(256) void heads_k(const float* __restrict__ rpn,
                                               const float* __restrict__ cls_w,
                                               const float* __restrict__ cls_b,
                                               const float* __restrict__ bbox_w,
                                               const float* __restrict__ bbox_b,
                                               float4* __restrict__ boxes,
                                               float* __restrict__ scores,
                                               u64* __restrict__ keys) {
  __shared__ float sf[32][260];
  __shared__ float so[45][33];
  int tid = threadIdx.x;
  int px0 = blockIdx.x * 32;
  for (int idx = tid; idx < 8192; idx += 256) {
    int c = idx >> 5, p = idx & 31;
    sf[p][c] = rpn[(size_t)c * NPX + px0 + p];
  }
  __syncthreads();
  int p = tid & 31, g = tid >> 5;
  for (int oi = 0; oi < 6; oi++) {
    int o = g + oi * 8;
    if (o >= 45) break;
    const float* wr = (o < 9) ? (cls_w + o * CC) : (bbox_w + (o - 9) * CC);
    float bsum = (o < 9) ? cls_b[o] : bbox_b[o - 9];
    float s = 0.f;
    for (int c = 0; c < CC; c += 4) {
      float4 f = *(const float4*)&sf[p][c];
      float4 wv = *(const float4*)&wr[c];
      s += f.x * wv.x; s += f.y * wv.y; s += f.z * wv.z; s += f.w * wv.w;
    }
    so[o][p] = s + bsum;
  }
  __syncthreads();
  for (int t = tid; t < 288; t += 256) {
    int a = t >> 5, pp = t & 31;
    int px = px0 + pp;
    int y = px / 160, x = px - y * 160;
    float logit = so[a][pp];
    float sc = 1.f / (1.f + expf(-logit));
    float ddx = so[9 + 4 * a][pp], ddy = so[10 + 4 * a][pp];
    float ddw = fminf(so[11 + 4 * a][pp], DWH);
    float ddh = fminf(so[12 + 4 * a][pp], DWH);
    float ax1 = x * 16.f + c_bx1[a];
    float ay1 = y * 16.f + c_by1[a];
    float ax2 = x * 16.f + c_bx2[a];
    float ay2 = y * 16.f + c_by2[a];
    float aw = ax2 - ax1, ah = ay2 - ay1;
    float cx = ax1 + 0.5f * aw, cy = ay1 + 0.5f * ah;
    float pcx = ddx * aw + cx, pcy = ddy * ah + cy;
    float pw = expf(ddw) * aw, phh = expf(ddh) * ah;
    float x1 = pcx - 0.5f * pw, y1 = pcy - 0.5f * phh;
    float x2 = pcx + 0.5f * pw, y2 = pcy + 0.5f * phh;
    x1 = fminf(fmaxf(x1, 0.f), IMS); x2 = fminf(fmaxf(x2, 0.f), IMS);
    y1 = fminf(fmaxf(y1, 0.f), IMS); y2 = fminf(fmaxf(y2, 0.f), IMS);
    int gidx = px * 9 + a;
    boxes[gidx] = make_float4(x1, y1, x2, y2);
    scores[gidx] = sc;
    u32 sb = __float_as_uint(sc);
    u32 mono = (sb & 0x80000000u) ? ~sb : (sb | 0x80000000u);
    keys[gidx] = ((u64)mono << 32) | (u64)(0xFFFFFFFFu - (u32)gidx);
  }
}

// ---------------- 3. grid-wide radix select (R8 split hist/scan) ----------------
__global__ __launch_bounds__(256) void hist_k(const u64* __restrict__ keys,
                                              const SelState* __restrict__ st,
                                              u32* __restrict__ hist,
                                              int wbits, int bitsdone) {
  int idx = blockIdx.x * 256 + threadIdx.x;  // grid 900 -> exactly 230400
  int lane = threadIdx.x & 63;
  u64 k = keys[idx];
  int shift = 64 - bitsdone - wbits;
  bool active = true;
  if (bitsdone > 0) active = ((k >> (64 - bitsdone)) == st->prefix);
  u32 digit = (u32)((k >> shift) & (u64)((1 << wbits) - 1));
  u64 act = __ballot(active);
  u64 todo = act;
  while (todo) {
    int src = __builtin_ctzll(todo);
    u32 d0 = (u32)__shfl((int)digit, src, 64);
    u64 m = __ballot(digit == d0) & act;
    if (lane == src) atomicAdd(&hist[d0], (u32)__popcll(m & todo));
    todo &= ~m;
  }
}

__global__ __launch_bounds__(1024) void scan_k(const u32* __restrict__ hist,
                                               SelState* st, int wbits) {
  __shared__ u32 tsum[1024];
  __shared__ u32 wsum[16];
  int tid = threadIdx.x;
  int lane = tid & 63, wv = tid >> 6;
  int nbins = 1 << wbits;
  int bpt = nbins >> 10;
  u32 r = st->r;
  u32 s = 0;
  for (int b = 0; b < bpt; b++) s += hist[tid * bpt + b];
  tsum[tid] = s;
  u32 v = s;
#pragma unroll
  for (int off = 1; off < 64; off <<= 1) v += (u32)__shfl_xor((int)v, off, 64);
  if (lane == 0) wsum[wv] = v;
  __syncthreads();
  if (tid == 0) {
    u32 cum = 0;
    int ws = 15;
    while (ws > 0 && cum + wsum[ws] < r) { cum += wsum[ws]; ws--; }
    int t = ws * 64 + 63, tend = ws * 64;
    while (t > tend && cum + tsum[t] < r) { cum += tsum[t]; t--; }
    int b = t * bpt + bpt - 1, bend = t * bpt;
    while (b > bend && cum + hist[b] < r) { cum += hist[b]; b--; }
    st->prefix = (st->prefix << wbits) | (u64)(u32)b;
    st->r = r - cum;
  }
}

// ---------------- 3b. compact: block-aggregated atomic ----------------
__global__ __launch_bounds__(256) void compact_k(const u64* __restrict__ keys,
                                                 SelState* st, u64* __restrict__ selk) {
  __shared__ u32 wbase[4];
  __shared__ u32 blkbase;
  int tid = threadIdx.x;
  int lane = tid & 63, wv = tid >> 6;
  int idx = blockIdx.x * 256 + tid;
  u64 k = keys[idx];
  bool sel = (k >= st->prefix);
  u64 m = __ballot(sel);
  u32 wcnt = (u32)__popcll(m);
  u32 before = (u32)__popcll(m & ((1ull << lane) - 1ull));
  if (lane == 0) wbase[wv] = wcnt;
  __syncthreads();
  if (tid == 0) {
    u32 b0 = wbase[0], b1 = wbase[1], b2 = wbase[2], b3 = wbase[3];
    u32 tot = b0 + b1 + b2 + b3;
    blkbase = tot ? atomicAdd(&st->cnt, tot) : 0u;
    wbase[0] = 0; wbase[1] = b0; wbase[2] = b0 + b1; wbase[3] = b0 + b1 + b2;
  }
  __syncthreads();
  if (sel) selk[blkbase + wbase[wv] + before] = k;
}

// ---------------- 4. exact rank -> sorted SoA ----------------
__global__ __launch_bounds__(64) void rank_k(const u64* __restrict__ selk,
                                             const float4* __restrict__ boxes,
                                             const float* __restrict__ scores,
                                             float* sx1, float* sy1, float* sx2, float* sy2, float* ssc) {
  __shared__ __align__(16) u64 sk[SEL_PAD];
  int lane = threadIdx.x;
  for (int i = lane; i < SEL_PAD; i += 64) sk[i] = (i < K_SEL) ? selk[i] : 0ull;
  __syncthreads();
  int n = blockIdx.x * 64 + lane;
  u64 myk = (n < K_SEL) ? selk[n] : ~0ull;
  int cnt = 0;
  const ulonglong2* sk2 = (const ulonglong2*)sk;
#pragma unroll 8
  for (int j = 0; j < SEL_PAD / 2; j++) {
    ulonglong2 kk = sk2[j];
    cnt += (kk.x > myk) ? 1 : 0;
    cnt += (kk.y > myk) ? 1 : 0;
  }
  if (n < K_SEL) {
    u32 oidx = 0xFFFFFFFFu - (u32)(myk & 0xFFFFFFFFull);
    float4 b = boxes[oidx];
    sx1[cnt] = b.x; sy1[cnt] = b.y; sx2[cnt] = b.z; sy2[cnt] = b.w;
    ssc[cnt] = scores[oidx];
  }
}

// ---------------- 5. pairwise suppression mask (ROW-major: maskR[i][w]) ----------------
__global__ __launch_bounds__(256) void mask_k(const float* __restrict__ sx1, const float* __restrict__ sy1,
                                              const float* __restrict__ sx2, const float* __restrict__ sy2,
                                              u64* __restrict__ maskR) {
  __shared__ float jb[5][3008];
  int tid = threadIdx.x;
  int wv = tid >> 6, lane = tid & 63;
  int ibase = blockIdx.x * 32 + wv * 8;
  float ix1[8], iy1[8], ix2[8], iy2[8], ia[8];
#pragma unroll
  for (int r = 0; r < 8; r++) {
    int i = ibase + r;
    ix1[r] = sx1[i]; iy1[r] = sy1[i]; ix2[r] = sx2[i]; iy2[r] = sy2[i];
    ia[r] = (ix2[r] - ix1[r]) * (iy2[r] - iy1[r]);
  }
  for (int half = 0; half < 2; half++) {
    int j0 = half * 3008;
    __syncthreads();
    for (int idx = tid; idx < 3008; idx += 256) {
      int j = j0 + idx;
      bool v = j < K_SEL;
      float a = v ? sx1[j] : 0.f;
      float b = v ? sy1[j] : 0.f;
      float c = v ? sx2[j] : 0.f;
      float d = v ? sy2[j] : 0.f;
      jb[0][idx] = a; jb[1][idx] = b; jb[2][idx] = c; jb[3][idx] = d;
      jb[4][idx] = (c - a) * (d - b);
    }
    __syncthreads();
    for (int wi = 0; wi < 47; wi++) {
      int w = half * 47 + wi;
      int jl = wi * 64 + lane;
      int j = j0 + jl;
      float jx1 = jb[0][jl], jy1 = jb[1][jl], jx2 = jb[2][jl], jy2 = jb[3][jl], ja = jb[4][jl];
      bool jv = j < K_SEL;
#pragma unroll
      for (int r = 0; r < 8; r++) {
        int i = ibase + r;
        float xl = fmaxf(ix1[r], jx1), yt = fmaxf(iy1[r], jy1);
        float xr = fminf(ix2[r], jx2), yb = fminf(iy2[r], jy2);
        float iw = fmaxf(xr - xl, 0.f), ihh = fmaxf(yb - yt, 0.f);
        float inter = iw * ihh;
        bool sup = jv && (j > i) && (inter > 0.7f * (ia[r] + ja - inter));
        u64 bits = __ballot(sup);
        if (lane == 0 && i < K_SEL) maskR[(size_t)i * 94 + w] = bits;
      }
    }
  }
}

// ---------------- 6. greedy NMS: PIPELINED tile prefetch + dead bitmap ----------------
// R12 post-mortem: nmsf = 642us @ VALUBusy 0.026% — kept-row global reads
// were serial per column. Fix: process in 94 blocks of 64 candidates; while
// block c is walked/OR-reduced, all 1024 threads hold block c+1's 64x94-word
// row tile (48KB contiguous) in registers (6 u64/thread, issued at iteration
// top -> latency hidden under walk+OR). Single LDS tile buffer; diag comes
// from tile[l*94+c] (no separate sdiag). OR-reduce: 94x16 (word,row-quad)
// tasks, skept-masked, LDS atomicOr into dead bitmap. dead == OR of all
// previously-kept rows == old supp -> kept set bit-identical -> absmax 0.0.
// Falsifier: WRITE_SIZE must stay ~0 (no spill; R4 lesson).
__global__ __launch_bounds__(1024) void nmsf_k(const u64* __restrict__ maskR,
                                               const float* __restrict__ sx1, const float* __restrict__ sy1,
                                               const float* __restrict__ sx2, const float* __restrict__ sy2,
                                               const float* __restrict__ ssc, float* __restrict__ out) {
  __shared__ u64 tile[6016];        // 64 rows x 94 words, row-major (48,128 B)
  __shared__ u64 skept[96];
  __shared__ u64 svalid[94];
  __shared__ u32 dead32[188];
  __shared__ u32 pre[95];
  int tid = threadIdx.x;
  int wv = tid >> 6, lane = tid & 63;

  if (tid < 96) skept[tid] = 0ull;
  if (tid < 188) dead32[tid] = 0u;
  for (int w = wv; w < 94; w += 16) {
    int p = w * 64 + lane;
    float bw = sx2[p] - sx1[p], bh = sy2[p] - sy1[p];
    bool ok = (p < K_SEL) && (bw >= 16.f) && (bh >= 16.f);
    u64 bits = __ballot(ok);
    if (lane == 0) svalid[w] = bits;
  }
  // prologue: tile 0 -> regs -> LDS
  u64 stg[6];
#pragma unroll
  for (int j = 0; j < 6; j++) {
    int i = tid + j * 1024;
    stg[j] = (i < 6016) ? maskR[i] : 0ull;
  }
#pragma unroll
  for (int j = 0; j < 6; j++) {
    int i = tid + j * 1024;
    if (i < 6016) tile[i] = stg[j];
  }
  __syncthreads();

  for (int c = 0; c < 94; c++) {
    // issue next tile's global loads (latency hidden under walk + OR below)
    if (c < 93) {
      const u64* tb = maskR + (size_t)(c + 1) * 6016;
#pragma unroll
      for (int j = 0; j < 6; j++) {
        int i = tid + j * 1024;
        stg[j] = (i < 6016) ? tb[i] : 0ull;
      }
    }
    // greedy walk on wave 0 (LDS only) — bit-identical to prior rounds
    if (wv == 0) {
      u64 deadc = ((u64)dead32[2 * c + 1] << 32) | (u64)dead32[2 * c];
      u64 cur = svalid[c] & ~deadc;
      u64 d = tile[lane * 94 + c];
      u64 rem = cur, kept = 0;
      while (rem) {
        int b = __builtin_ctzll(rem);
        kept |= (1ull << b);
        u64 dd = shfl64(d, b);
        rem &= ~dd;
        rem &= ~(1ull << b);
      }
      if (lane == 0) skept[c] = kept;
    }
    __syncthreads();
    // OR kept rows into dead (parallel, LDS only)
    u64 km = skept[c];
    if (km) {
      for (int idx = tid; idx < 94 * 16; idx += 1024) {
        int w = idx % 94, g = idx / 94;
        u64 acc = 0;
#pragma unroll
        for (int q = 0; q < 4; q++) {
          int l = g * 4 + q;
          if ((km >> l) & 1ull) acc |= tile[l * 94 + w];
        }
        if (acc) {
          u32 alo = (u32)acc, ahi = (u32)(acc >> 32);
          if (alo) atomicOr(&dead32[2 * w], alo);
          if (ahi) atomicOr(&dead32[2 * w + 1], ahi);
        }
      }
    }
    __syncthreads();
    // write next tile (all reads of current tile complete)
    if (c < 93) {
#pragma unroll
      for (int j = 0; j < 6; j++) {
        int i = tid + j * 1024;
        if (i < 6016) tile[i] = stg[j];
      }
      __syncthreads();
    }
  }

  // ---- finalize (identical outputs to split final_k) ----
  if (tid == 0) {
    u32 s = 0;
    for (int w = 0; w < 94; w++) { pre[w] = s; s += (u32)__popcll(skept[w]); }
    pre[94] = s;
  }
  __syncthreads();
  u32 total = pre[94];
  for (int p = tid; p < K_SEL; p += 1024) {
    int w = p >> 6, b = p & 63;
    u64 word = skept[w];
    u32 kb = pre[w] + (u32)__popcll(word & ((1ull << b) - 1ull));
    bool kept = (word >> b) & 1ull;
    int slot = -1; float sc = -1.f;
    if (kept) {
      if (kb < 300) { slot = (int)kb; sc = ssc[p]; }
    } else {
      u32 s2 = total + (u32)p - kb;
      if (s2 < 300) slot = (int)s2;
    }
    if (slot >= 0) {
      out[slot * 5 + 0] = sx1[p];
      out[slot * 5 + 1] = sy1[p];
      out[slot * 5 + 2] = sx2[p];
      out[slot * 5 + 3] = sy2[p];
      out[slot * 5 + 4] = sc;
    }
  }
}

extern "C" void kernel_launch(void* const* d_in, const int* in_sizes, int n_in,
                              void* d_out, int out_size, void* d_ws, size_t ws_size,
                              hipStream_t stream) {
  const float* feat   = (const float*)d_in[0];
  const float* conv_w = (const float*)d_in[2];
  const float* conv_b = (const float*)d_in[3];
  const float* cls_w  = (const float*)d_in[4];
  const float* cls_b  = (const float*)d_in[5];
  const float* bbox_w = (const float*)d_in[6];
  const float* bbox_b = (const float*)d_in[7];
  float* out = (float*)d_out;
  char* ws = (char*)d_ws;

  float*  rpn    = (float*)(ws + OFF_RPN);
  float4* boxes  = (float4*)(ws + OFF_BOXES);
  float*  scores = (float*)(ws + OFF_SCORES);
  u64*    keys   = (u64*)(ws + OFF_KEYS);
  SelState* st   = (SelState*)(ws + OFF_STATE);
  u64*    selk   = (u64*)(ws + OFF_SELK);
  float*  sx1    = (float*)(ws + OFF_SX1);
  float*  sy1    = (float*)(ws + OFF_SY1);
  float*  sx2    = (float*)(ws + OFF_SX2);
  float*  sy2    = (float*)(ws + OFF_SY2);
  float*  ssc    = (float*)(ws + OFF_SSC);
  u64*    maskR  = (u64*)(ws + OFF_MASKR);
  float*  wT     = (float*)(ws + OFF_WT);
  u32*    hist   = (u32*)(ws + OFF_HIST);

  wtrz_k<<<184, 256, 0, stream>>>(conv_w, wT, hist, st);
  conv_k<<<800, 256, 0, stream>>>(feat, wT, conv_b, rpn);
  heads_k<<<800, 256, 0, stream>>>(rpn, cls_w, cls_b, bbox_w, bbox_b, boxes, scores, keys);

  hist_k<<<900, 256, 0, stream>>>(keys, st, hist,         13,  0);
  scan_k<<<1, 1024, 0, stream>>>(hist,         st, 13);
  hist_k<<<900, 256, 0, stream>>>(keys, st, hist +  8192, 13, 13);
  scan_k<<<1, 1024, 0, stream>>>(hist +  8192, st, 13);
  hist_k<<<900, 256, 0, stream>>>(keys, st, hist + 16384, 13, 26);
  scan_k<<<1, 1024, 0, stream>>>(hist + 16384, st, 13);
  hist_k<<<900, 256, 0, stream>>>(keys, st, hist + 24576, 13, 39);
  scan_k<<<1, 1024, 0, stream>>>(hist + 24576, st, 13);
  hist_k<<<900, 256, 0, stream>>>(keys, st, hist + 32768, 12, 52);
  scan_k<<<1, 1024, 0, stream>>>(hist + 32768, st, 12);

  compact_k<<<900, 256, 0, stream>>>(keys, st, selk);
  rank_k<<<94, 64, 0, stream>>>(selk, boxes, scores, sx1, sy1, sx2, sy2, ssc);
  mask_k<<<188, 256, 0, stream>>>(sx1, sy1, sx2, sy2, maskR);
  nmsf_k<<<1, 1024, 0, stream>>>(maskR, sx1, sy1, sx2, sy2, ssc, out);
}

// Round 14
// 1133.148 us; speedup vs baseline: 1.4407x; 1.2340x over previous
//
#include <hip/hip_runtime.h>
#include <math.h>

typedef unsigned long long u64;
typedef unsigned int u32;

#define HH 160
#define WW 160
#define CC 256
#define NPX 25600
#define NA 9
#define NSC 230400
#define K_SEL 6000
#define SEL_PAD 6016
#define IMS 2560.0f
#define DWH 4.135166556742356f

struct SelState { u64 prefix; u32 r; u32 cnt; };

// ---- ws layout (bytes) ----
#define OFF_BOXES   0u               // float4[230400] -> 3,686,400
#define OFF_SCORES  3686400u         // float [230400]
#define OFF_KEYS    4608000u         // u64   [230400]
#define OFF_STATE   7499776u
#define OFF_SELK    7500032u         // u64[6016]
#define OFF_SX1     7548160u
#define OFF_SY1     7572224u
#define OFF_SX2     7596288u
#define OFF_SY2     7620352u
#define OFF_SSC     7644416u
#define OFF_MASKR   11503104u        // u64[6016*94] row-major -> 4,524,032
#define OFF_WT      16028160u        // float[2304*256] -> ends 18,387,456
#define OFF_HIST    18387456u        // u32[5*8192] -> ends 18,551,296
#define OFF_RPN     27869184u        // float[256*160*160] -> ends 54,083,584

__constant__ float c_bx1[9] = {-91.f,-181.f,-362.f,-64.f,-128.f,-256.f,-45.f,-91.f,-181.f};
__constant__ float c_by1[9] = {-45.f,-91.f,-181.f,-64.f,-128.f,-256.f,-91.f,-181.f,-362.f};
__constant__ float c_bx2[9] = { 91.f, 181.f, 362.f, 64.f, 128.f, 256.f, 45.f, 91.f, 181.f};
__constant__ float c_by2[9] = { 45.f,  91.f, 181.f, 64.f, 128.f, 256.f, 91.f, 181.f, 362.f};

__device__ inline u64 shfl64(u64 v, int src) {
  int lo = (int)(v & 0xFFFFFFFFull), hi = (int)(v >> 32);
  lo = __shfl(lo, src, 64); hi = __shfl(hi, src, 64);
  return ((u64)(u32)hi << 32) | (u32)lo;
}
__device__ inline u64 shfl64_up(u64 v, int delta) {
  int lo = __shfl_up((int)(v & 0xFFFFFFFFull), delta, 64);
  int hi = __shfl_up((int)(v >> 32), delta, 64);
  return ((u64)(u32)hi << 32) | (u32)lo;
}
__device__ inline u64 shfl64_xor(u64 v, int mask) {
  int lo = __shfl_xor((int)(v & 0xFFFFFFFFull), mask, 64);
  int hi = __shfl_xor((int)(v >> 32), mask, 64);
  return ((u64)(u32)hi << 32) | (u32)lo;
}

// ---------------- 0. weight transpose FUSED with hist/state zeroing ----------------
__global__ __launch_bounds__(256) void wtrz_k(const float* __restrict__ w, float* __restrict__ wT,
                                              u32* __restrict__ hist, SelState* st) {
  int b = blockIdx.x;
  int tid = threadIdx.x;
  if (b < 144) {
    __shared__ float t[64][65];
    int kb = b % 36;
    int ob = b / 36;
    for (int it = 0; it < 16; it++) {
      int idx = it * 256 + tid;
      int row = idx >> 6, colk = idx & 63;
      t[row][colk] = w[(size_t)(ob * 64 + row) * 2304 + kb * 64 + colk];
    }
    __syncthreads();
    for (int it = 0; it < 16; it++) {
      int idx = it * 256 + tid;
      int krow = idx >> 6, occ = idx & 63;
      wT[(size_t)(kb * 64 + krow) * 256 + ob * 64 + occ] = t[occ][krow];
    }
  } else {
    int zb = (b - 144) * 1024 + tid * 4;      // 40 blocks x 1024 = 40960 = 5*8192
    *(uint4*)&hist[zb] = make_uint4(0, 0, 0, 0);
    if (b == 144 && tid == 0) { st->prefix = 0; st->r = K_SEL; st->cnt = 0; }
  }
}

// ---------------- 1. conv3x3 + bias + relu (R1 scalar-weight, frozen at ~502us) ----------------
__global__ __launch_bounds__(256) void conv_k(const float* __restrict__ feat,
                                              const float* __restrict__ wT,
                                              const float* __restrict__ bias,
                                              float* __restrict__ outp) {
  int bx = blockIdx.x;              // 800 = 5 * 40 * 4
  int ct = bx % 5;
  int rt = (bx / 5) % 40;
  int ot = bx / 200;
  int x0 = ct * 32, y0 = rt * 4, oc0 = ot * 64;

  __shared__ float ps[2][8][6][36];

  int tid = threadIdx.x;
  int lane = tid & 63;
  int wvu = __builtin_amdgcn_readfirstlane(tid >> 6);   // wave id, SGPR-uniform
  int col = lane & 31;
  int s = lane >> 5;
  int ocw = oc0 + wvu * 16;

  int s_off[7]; int s_lof[7]; bool s_val[7];
#pragma unroll
  for (int it = 0; it < 7; it++) {
    int idx = tid + it * 256;
    bool ex = (idx < 1632);
    int icl = idx / 204, rem = idx % 204;
    int r = rem / 34, c = rem % 34;
    int gy = y0 + r - 1, gx = x0 + c - 1;
    s_val[it] = ex && ((unsigned)gy < 160u) && ((unsigned)gx < 160u);
    s_off[it] = icl * NPX + gy * WW + gx;
    s_lof[it] = ex ? ((icl * 6 + r) * 36 + c) : 0;
    if (!ex) s_lof[it] = -1;
  }

  float acc0[16], acc1[16];
#pragma unroll
  for (int i = 0; i < 16; i++) { acc0[i] = 0.f; acc1[i] = 0.f; }

  float st[7];
#pragma unroll
  for (int it = 0; it < 7; it++) {
    float v = 0.f;
    if (s_val[it]) v = feat[s_off[it]];
    if (s_lof[it] >= 0) (&ps[0][0][0][0])[s_lof[it]] = v;
  }
  __syncthreads();

  for (int c8 = 0; c8 < 32; c8++) {
    if (c8 < 31) {
      int icn = (c8 + 1) * 8;
#pragma unroll
      for (int it = 0; it < 7; it++) {
        st[it] = 0.f;
        if (s_val[it]) st[it] = feat[icn * NPX + s_off[it]];
      }
    }
    int buf = c8 & 1;
    int ic0 = c8 * 8;
    for (int icl = 0; icl < 8; icl++) {       // not unrolled: I-cache
      float p[4][3];
#pragma unroll
      for (int rr = 0; rr < 4; rr++)
#pragma unroll
        for (int cc = 0; cc < 3; cc++)
          p[rr][cc] = ps[buf][icl][2 * s + rr][col + cc];
      const float* wb = wT + (size_t)(ic0 + icl) * 9 * 256 + ocw;   // uniform addr
#pragma unroll
      for (int dy = 0; dy < 3; dy++) {
#pragma unroll
        for (int dx = 0; dx < 3; dx++) {
          const float* wr = wb + (dy * 3 + dx) * 256;
#pragma unroll
          for (int i = 0; i < 16; i++) {
            float wv_ = wr[i];                // s_load -> SGPR operand
            acc0[i] += wv_ * p[dy][dx];
            acc1[i] += wv_ * p[dy + 1][dx];
          }
        }
      }
    }
    if (c8 < 31) {
      __syncthreads();
      float* dst = &ps[buf ^ 1][0][0][0];
#pragma unroll
      for (int it = 0; it < 7; it++)
        if (s_lof[it] >= 0) dst[s_lof[it]] = st[it];
      __syncthreads();
    }
  }
#pragma unroll
  for (int i = 0; i < 16; i++) {
    int oc = ocw + i;
    float bv = bias[oc];
    size_t base = (size_t)oc * NPX + (y0 + 2 * s) * WW + x0 + col;
    outp[base] = fmaxf(acc0[i] + bv, 0.f);
    outp[base + WW] = fmaxf(acc1[i] + bv, 0.f);
  }
}

// ---------------- 2. heads + sigmoid + decode + clip + key ----------------
__global__ __launch_bounds__(256) void heads_k(const float* __restrict__ rpn,
                                               const float* __restrict__ cls_w,
                                               const float* __restrict__ cls_b,
                                               const float* __restrict__ bbox_w,
                                               const float* __restrict__ bbox_b,
                                               float4* __restrict__ boxes,
                                               float* __restrict__ scores,
                                               u64* __restrict__ keys) {
  __shared__ float sf[32][260];
  __shared__ float so[45][33];
  int tid = threadIdx.x;
  int px0 = blockIdx.x * 32;
  for (int idx = tid; idx < 8192; idx += 256) {
    int c = idx >> 5, p = idx & 31;
    sf[p][c] = rpn[(size_t)c * NPX + px0 + p];
  }
  __syncthreads();
  int p = tid & 31, g = tid >> 5;
  for (int oi = 0; oi < 6; oi++) {
    int o = g + oi * 8;
    if (o >= 45) break;
    const float* wr = (o < 9) ? (cls_w + o * CC) : (bbox_w + (o - 9) * CC);
    float bsum = (o < 9) ? cls_b[o] : bbox_b[o - 9];
    float s = 0.f;
    for (int c = 0; c < CC; c += 4) {
      float4 f = *(const float4*)&sf[p][c];
      float4 wv = *(const float4*)&wr[c];
      s += f.x * wv.x; s += f.y * wv.y; s += f.z * wv.z; s += f.w * wv.w;
    }
    so[o][p] = s + bsum;
  }
  __syncthreads();
  for (int t = tid; t < 288; t += 256) {
    int a = t >> 5, pp = t & 31;
    int px = px0 + pp;
    int y = px / 160, x = px - y * 160;
    float logit = so[a][pp];
    float sc = 1.f / (1.f + expf(-logit));
    float ddx = so[9 + 4 * a][pp], ddy = so[10 + 4 * a][pp];
    float ddw = fminf(so[11 + 4 * a][pp], DWH);
    float ddh = fminf(so[12 + 4 * a][pp], DWH);
    float ax1 = x * 16.f + c_bx1[a];
    float ay1 = y * 16.f + c_by1[a];
    float ax2 = x * 16.f + c_bx2[a];
    float ay2 = y * 16.f + c_by2[a];
    float aw = ax2 - ax1, ah = ay2 - ay1;
    float cx = ax1 + 0.5f * aw, cy = ay1 + 0.5f * ah;
    float pcx = ddx * aw + cx, pcy = ddy * ah + cy;
    float pw = expf(ddw) * aw, phh = expf(ddh) * ah;
    float x1 = pcx - 0.5f * pw, y1 = pcy - 0.5f * phh;
    float x2 = pcx + 0.5f * pw, y2 = pcy + 0.5f * phh;
    x1 = fminf(fmaxf(x1, 0.f), IMS); x2 = fminf(fmaxf(x2, 0.f), IMS);
    y1 = fminf(fmaxf(y1, 0.f), IMS); y2 = fminf(fmaxf(y2, 0.f), IMS);
    int gidx = px * 9 + a;
    boxes[gidx] = make_float4(x1, y1, x2, y2);
    scores[gidx] = sc;
    u32 sb = __float_as_uint(sc);
    u32 mono = (sb & 0x80000000u) ? ~sb : (sb | 0x80000000u);
    keys[gidx] = ((u64)mono << 32) | (u64)(0xFFFFFFFFu - (u32)gidx);
  }
}

// ---------------- 3. grid-wide radix select (R8 split hist/scan) ----------------
__global__ __launch_bounds__(256) void hist_k(const u64* __restrict__ keys,
                                              const SelState* __restrict__ st,
                                              u32* __restrict__ hist,
                                              int wbits, int bitsdone) {
  int idx = blockIdx.x * 256 + threadIdx.x;  // grid 900 -> exactly 230400
  int lane = threadIdx.x & 63;
  u64 k = keys[idx];
  int shift = 64 - bitsdone - wbits;
  bool active = true;
  if (bitsdone > 0) active = ((k >> (64 - bitsdone)) == st->prefix);
  u32 digit = (u32)((k >> shift) & (u64)((1 << wbits) - 1));
  u64 act = __ballot(active);
  u64 todo = act;
  while (todo) {
    int src = __builtin_ctzll(todo);
    u32 d0 = (u32)__shfl((int)digit, src, 64);
    u64 m = __ballot(digit == d0) & act;
    if (lane == src) atomicAdd(&hist[d0], (u32)__popcll(m & todo));
    todo &= ~m;
  }
}

__global__ __launch_bounds__(1024) void scan_k(const u32* __restrict__ hist,
                                               SelState* st, int wbits) {
  __shared__ u32 tsum[1024];
  __shared__ u32 wsum[16];
  int tid = threadIdx.x;
  int lane = tid & 63, wv = tid >> 6;
  int nbins = 1 << wbits;
  int bpt = nbins >> 10;
  u32 r = st->r;
  u32 s = 0;
  for (int b = 0; b < bpt; b++) s += hist[tid * bpt + b];
  tsum[tid] = s;
  u32 v = s;
#pragma unroll
  for (int off = 1; off < 64; off <<= 1) v += (u32)__shfl_xor((int)v, off, 64);
  if (lane == 0) wsum[wv] = v;
  __syncthreads();
  if (tid == 0) {
    u32 cum = 0;
    int ws = 15;
    while (ws > 0 && cum + wsum[ws] < r) { cum += wsum[ws]; ws--; }
    int t = ws * 64 + 63, tend = ws * 64;
    while (t > tend && cum + tsum[t] < r) { cum += tsum[t]; t--; }
    int b = t * bpt + bpt - 1, bend = t * bpt;
    while (b > bend && cum + hist[b] < r) { cum += hist[b]; b--; }
    st->prefix = (st->prefix << wbits) | (u64)(u32)b;
    st->r = r - cum;
  }
}

// ---------------- 3b. compact: block-aggregated atomic ----------------
__global__ __launch_bounds__(256) void compact_k(const u64* __restrict__ keys,
                                                 SelState* st, u64* __restrict__ selk) {
  __shared__ u32 wbase[4];
  __shared__ u32 blkbase;
  int tid = threadIdx.x;
  int lane = tid & 63, wv = tid >> 6;
  int idx = blockIdx.x * 256 + tid;
  u64 k = keys[idx];
  bool sel = (k >= st->prefix);
  u64 m = __ballot(sel);
  u32 wcnt = (u32)__popcll(m);
  u32 before = (u32)__popcll(m & ((1ull << lane) - 1ull));
  if (lane == 0) wbase[wv] = wcnt;
  __syncthreads();
  if (tid == 0) {
    u32 b0 = wbase[0], b1 = wbase[1], b2 = wbase[2], b3 = wbase[3];
    u32 tot = b0 + b1 + b2 + b3;
    blkbase = tot ? atomicAdd(&st->cnt, tot) : 0u;
    wbase[0] = 0; wbase[1] = b0; wbase[2] = b0 + b1; wbase[3] = b0 + b1 + b2;
  }
  __syncthreads();
  if (sel) selk[blkbase + wbase[wv] + before] = k;
}

// ---------------- 4. exact rank -> sorted SoA ----------------
__global__ __launch_bounds__(64) void rank_k(const u64* __restrict__ selk,
                                             const float4* __restrict__ boxes,
                                             const float* __restrict__ scores,
                                             float* sx1, float* sy1, float* sx2, float* sy2, float* ssc) {
  __shared__ __align__(16) u64 sk[SEL_PAD];
  int lane = threadIdx.x;
  for (int i = lane; i < SEL_PAD; i += 64) sk[i] = (i < K_SEL) ? selk[i] : 0ull;
  __syncthreads();
  int n = blockIdx.x * 64 + lane;
  u64 myk = (n < K_SEL) ? selk[n] : ~0ull;
  int cnt = 0;
  const ulonglong2* sk2 = (const ulonglong2*)sk;
#pragma unroll 8
  for (int j = 0; j < SEL_PAD / 2; j++) {
    ulonglong2 kk = sk2[j];
    cnt += (kk.x > myk) ? 1 : 0;
    cnt += (kk.y > myk) ? 1 : 0;
  }
  if (n < K_SEL) {
    u32 oidx = 0xFFFFFFFFu - (u32)(myk & 0xFFFFFFFFull);
    float4 b = boxes[oidx];
    sx1[cnt] = b.x; sy1[cnt] = b.y; sx2[cnt] = b.z; sy2[cnt] = b.w;
    ssc[cnt] = scores[oidx];
  }
}

// ---------------- 5. pairwise suppression mask (ROW-major: maskR[i][w]) ----------------
__global__ __launch_bounds__(256) void mask_k(const float* __restrict__ sx1, const float* __restrict__ sy1,
                                              const float* __restrict__ sx2, const float* __restrict__ sy2,
                                              u64* __restrict__ maskR) {
  __shared__ float jb[5][3008];
  int tid = threadIdx.x;
  int wv = tid >> 6, lane = tid & 63;
  int ibase = blockIdx.x * 32 + wv * 8;
  float ix1[8], iy1[8], ix2[8], iy2[8], ia[8];
#pragma unroll
  for (int r = 0; r < 8; r++) {
    int i = ibase + r;
    ix1[r] = sx1[i]; iy1[r] = sy1[i]; ix2[r] = sx2[i]; iy2[r] = sy2[i];
    ia[r] = (ix2[r] - ix1[r]) * (iy2[r] - iy1[r]);
  }
  for (int half = 0; half < 2; half++) {
    int j0 = half * 3008;
    __syncthreads();
    for (int idx = tid; idx < 3008; idx += 256) {
      int j = j0 + idx;
      bool v = j < K_SEL;
      float a = v ? sx1[j] : 0.f;
      float b = v ? sy1[j] : 0.f;
      float c = v ? sx2[j] : 0.f;
      float d = v ? sy2[j] : 0.f;
      jb[0][idx] = a; jb[1][idx] = b; jb[2][idx] = c; jb[3][idx] = d;
      jb[4][idx] = (c - a) * (d - b);
    }
    __syncthreads();
    for (int wi = 0; wi < 47; wi++) {
      int w = half * 47 + wi;
      int jl = wi * 64 + lane;
      int j = j0 + jl;
      float jx1 = jb[0][jl], jy1 = jb[1][jl], jx2 = jb[2][jl], jy2 = jb[3][jl], ja = jb[4][jl];
      bool jv = j < K_SEL;
#pragma unroll
      for (int r = 0; r < 8; r++) {
        int i = ibase + r;
        float xl = fmaxf(ix1[r], jx1), yt = fmaxf(iy1[r], jy1);
        float xr = fminf(ix2[r], jx2), yb = fminf(iy2[r], jy2);
        float iw = fmaxf(xr - xl, 0.f), ihh = fmaxf(yb - yt, 0.f);
        float inter = iw * ihh;
        bool sup = jv && (j > i) && (inter > 0.7f * (ia[r] + ja - inter));
        u64 bits = __ballot(sup);
        if (lane == 0 && i < K_SEL) maskR[(size_t)i * 94 + w] = bits;
      }
    }
  }
}

// ---------------- 6. greedy NMS: pipelined tiles + PARALLEL-PEELING walk ----------------
// R13 post-mortem: two structurally different NMS variants both land ~408us
// -> shared serial greedy walk is the floor (sparse suppression -> ~5000 kept
// x ~170cy dependent shfl chain ~ 370us, matches). Replace the per-element
// walk with parallel peeling (provably == sequential greedy): per round,
// safe = {b in cur : no earlier cur-member suppresses b} via 6-step lane
// prefix-OR of diag rows; kept += safe; cur &= ~safe & ~(OR d[safe]).
// min(cur) is always safe -> terminates; same-round earlier safe suppressor
// excludes b -> exact greedy semantics -> kept set bit-identical -> absmax 0.
// Sparse data: ~1-2 rounds/column x ~26 shfls vs ~55 x 170cy serial.
// Tile prefetch pipeline + OR phase + finalize unchanged from R13.
__global__ __launch_bounds__(1024) void nmsf_k(const u64* __restrict__ maskR,
                                               const float* __restrict__ sx1, const float* __restrict__ sy1,
                                               const float* __restrict__ sx2, const float* __restrict__ sy2,
                                               const float* __restrict__ ssc, float* __restrict__ out) {
  __shared__ u64 tile[6016];        // 64 rows x 94 words, row-major (48,128 B)
  __shared__ u64 skept[96];
  __shared__ u64 svalid[94];
  __shared__ u32 dead32[188];
  __shared__ u32 pre[95];
  int tid = threadIdx.x;
  int wv = tid >> 6, lane = tid & 63;

  if (tid < 96) skept[tid] = 0ull;
  if (tid < 188) dead32[tid] = 0u;
  for (int w = wv; w < 94; w += 16) {
    int p = w * 64 + lane;
    float bw = sx2[p] - sx1[p], bh = sy2[p] - sy1[p];
    bool ok = (p < K_SEL) && (bw >= 16.f) && (bh >= 16.f);
    u64 bits = __ballot(ok);
    if (lane == 0) svalid[w] = bits;
  }
  // prologue: tile 0 -> regs -> LDS
  u64 stg[6];
#pragma unroll
  for (int j = 0; j < 6; j++) {
    int i = tid + j * 1024;
    stg[j] = (i < 6016) ? maskR[i] : 0ull;
  }
#pragma unroll
  for (int j = 0; j < 6; j++) {
    int i = tid + j * 1024;
    if (i < 6016) tile[i] = stg[j];
  }
  __syncthreads();

  for (int c = 0; c < 94; c++) {
    // issue next tile's global loads (latency hidden under walk + OR below)
    if (c < 93) {
      const u64* tb = maskR + (size_t)(c + 1) * 6016;
#pragma unroll
      for (int j = 0; j < 6; j++) {
        int i = tid + j * 1024;
        stg[j] = (i < 6016) ? tb[i] : 0ull;
      }
    }
    // parallel-peeling greedy on wave 0 (LDS + shfl only)
    if (wv == 0) {
      u64 deadc = ((u64)dead32[2 * c + 1] << 32) | (u64)dead32[2 * c];
      u64 cur = svalid[c] & ~deadc;
      u64 d = tile[lane * 94 + c];
      u64 kept = 0;
      while (cur) {
        // inclusive prefix-OR over lanes of (lane in cur ? d : 0)
        u64 inc = ((cur >> lane) & 1ull) ? d : 0ull;
#pragma unroll
        for (int off = 1; off < 64; off <<= 1) {
          u64 t = shfl64_up(inc, off);
          if (lane >= off) inc |= t;
        }
        u64 ex = shfl64_up(inc, 1);
        if (lane == 0) ex = 0ull;
        bool in_cur = (cur >> lane) & 1ull;
        bool suppd = (ex >> lane) & 1ull;
        u64 safe = __ballot(in_cur && !suppd);
        // dead_new = OR of d over safe lanes
        u64 y = ((safe >> lane) & 1ull) ? d : 0ull;
#pragma unroll
        for (int off = 1; off < 64; off <<= 1) y |= shfl64_xor(y, off);
        kept |= safe;
        cur &= ~safe;
        cur &= ~y;
      }
      if (lane == 0) skept[c] = kept;
    }
    __syncthreads();
    // OR kept rows into dead (parallel, LDS only)
    u64 km = skept[c];
    if (km) {
      for (int idx = tid; idx < 94 * 16; idx += 1024) {
        int w = idx % 94, g = idx / 94;
        u64 acc = 0;
#pragma unroll
        for (int q = 0; q < 4; q++) {
          int l = g * 4 + q;
          if ((km >> l) & 1ull) acc |= tile[l * 94 + w];
        }
        if (acc) {
          u32 alo = (u32)acc, ahi = (u32)(acc >> 32);
          if (alo) atomicOr(&dead32[2 * w], alo);
          if (ahi) atomicOr(&dead32[2 * w + 1], ahi);
        }
      }
    }
    __syncthreads();
    // write next tile (all reads of current tile complete)
    if (c < 93) {
#pragma unroll
      for (int j = 0; j < 6; j++) {
        int i = tid + j * 1024;
        if (i < 6016) tile[i] = stg[j];
      }
      __syncthreads();
    }
  }

  // ---- finalize (identical outputs to split final_k) ----
  if (tid == 0) {
    u32 s = 0;
    for (int w = 0; w < 94; w++) { pre[w] = s; s += (u32)__popcll(skept[w]); }
    pre[94] = s;
  }
  __syncthreads();
  u32 total = pre[94];
  for (int p = tid; p < K_SEL; p += 1024) {
    int w = p >> 6, b = p & 63;
    u64 word = skept[w];
    u32 kb = pre[w] + (u32)__popcll(word & ((1ull << b) - 1ull));
    bool kept = (word >> b) & 1ull;
    int slot = -1; float sc = -1.f;
    if (kept) {
      if (kb < 300) { slot = (int)kb; sc = ssc[p]; }
    } else {
      u32 s2 = total + (u32)p - kb;
      if (s2 < 300) slot = (int)s2;
    }
    if (slot >= 0) {
      out[slot * 5 + 0] = sx1[p];
      out[slot * 5 + 1] = sy1[p];
      out[slot * 5 + 2] = sx2[p];
      out[slot * 5 + 3] = sy2[p];
      out[slot * 5 + 4] = sc;
    }
  }
}

extern "C" void kernel_launch(void* const* d_in, const int* in_sizes, int n_in,
                              void* d_out, int out_size, void* d_ws, size_t ws_size,
                              hipStream_t stream) {
  const float* feat   = (const float*)d_in[0];
  const float* conv_w = (const float*)d_in[2];
  const float* conv_b = (const float*)d_in[3];
  const float* cls_w  = (const float*)d_in[4];
  const float* cls_b  = (const float*)d_in[5];
  const float* bbox_w = (const float*)d_in[6];
  const float* bbox_b = (const float*)d_in[7];
  float* out = (float*)d_out;
  char* ws = (char*)d_ws;

  float*  rpn    = (float*)(ws + OFF_RPN);
  float4* boxes  = (float4*)(ws + OFF_BOXES);
  float*  scores = (float*)(ws + OFF_SCORES);
  u64*    keys   = (u64*)(ws + OFF_KEYS);
  SelState* st   = (SelState*)(ws + OFF_STATE);
  u64*    selk   = (u64*)(ws + OFF_SELK);
  float*  sx1    = (float*)(ws + OFF_SX1);
  float*  sy1    = (float*)(ws + OFF_SY1);
  float*  sx2    = (float*)(ws + OFF_SX2);
  float*  sy2    = (float*)(ws + OFF_SY2);
  float*  ssc    = (float*)(ws + OFF_SSC);
  u64*    maskR  = (u64*)(ws + OFF_MASKR);
  float*  wT     = (float*)(ws + OFF_WT);
  u32*    hist   = (u32*)(ws + OFF_HIST);

  wtrz_k<<<184, 256, 0, stream>>>(conv_w, wT, hist, st);
  conv_k<<<800, 256, 0, stream>>>(feat, wT, conv_b, rpn);
  heads_k<<<800, 256, 0, stream>>>(rpn, cls_w, cls_b, bbox_w, bbox_b, boxes, scores, keys);

  hist_k<<<900, 256, 0, stream>>>(keys, st, hist,         13,  0);
  scan_k<<<1, 1024, 0, stream>>>(hist,         st, 13);
  hist_k<<<900, 256, 0, stream>>>(keys, st, hist +  8192, 13, 13);
  scan_k<<<1, 1024, 0, stream>>>(hist +  8192, st, 13);
  hist_k<<<900, 256, 0, stream>>>(keys, st, hist + 16384, 13, 26);
  scan_k<<<1, 1024, 0, stream>>>(hist + 16384, st, 13);
  hist_k<<<900, 256, 0, stream>>>(keys, st, hist + 24576, 13, 39);
  scan_k<<<1, 1024, 0, stream>>>(hist + 24576, st, 13);
  hist_k<<<900, 256, 0, stream>>>(keys, st, hist + 32768, 12, 52);
  scan_k<<<1, 1024, 0, stream>>>(hist + 32768, st, 12);

  compact_k<<<900, 256, 0, stream>>>(keys, st, selk);
  rank_k<<<94, 64, 0, stream>>>(selk, boxes, scores, sx1, sy1, sx2, sy2, ssc);
  mask_k<<<188, 256, 0, stream>>>(sx1, sy1, sx2, sy2, maskR);
  nmsf_k<<<1, 1024, 0, stream>>>(maskR, sx1, sy1, sx2, sy2, ssc, out);
}